// Round 2
// baseline (1972.514 us; speedup 1.0000x reference)
//
#include <hip/hip_runtime.h>

#define NN 50000
#define NE 800000
#define NG 128
#define NL 3

typedef __attribute__((ext_vector_type(8))) short short8;
typedef __attribute__((ext_vector_type(4))) float f32x4;
typedef __attribute__((ext_vector_type(4))) int i32x4;

union FragU { i32x4 i; short8 s; };

__device__ __forceinline__ float silu_f(float x) { return x / (1.f + __expf(-x)); }
__device__ __forceinline__ float rdl(float v, int l) {
  return __int_as_float(__builtin_amdgcn_readlane(__float_as_int(v), l));
}
__device__ __forceinline__ float wave_sum(float v) {
#pragma unroll
  for (int m = 1; m < 64; m <<= 1) v += __shfl_xor(v, m, 64);
  return v;
}

__device__ __forceinline__ unsigned f2u(float x) { return __float_as_uint(x); }
__device__ __forceinline__ float hi_part(float x) {
  return __uint_as_float(f2u(x) & 0xffff0000u);
}
// pack two fp32 -> (bf16,bf16) dword via truncation; e0 in low half
__device__ __forceinline__ unsigned pk_hi(float e0, float e1) {
  return __builtin_amdgcn_perm(f2u(e1), f2u(e0), 0x07060302u);
}

__device__ __forceinline__ f32x4 mfma16(i32x4 a, i32x4 b, f32x4 c) {
  FragU ua, ub; ua.i = a; ub.i = b;
  return __builtin_amdgcn_mfma_f32_16x16x32_bf16(ua.s, ub.s, c, 0, 0, 0);
}

// split 8 fp32 into hi/lo bf16x8 fragments (A-frag element order: k ascending)
__device__ __forceinline__ void split8(const float* x, i32x4& fh, i32x4& fl) {
#pragma unroll
  for (int i = 0; i < 4; ++i) {
    const float a = x[2 * i], b = x[2 * i + 1];
    fh[i] = (int)pk_hi(a, b);
    fl[i] = (int)pk_hi(a - hi_part(a), b - hi_part(b));
  }
}

// build B-frag (hi/lo) for W[k][n] tile: rows k0..k0+31, cols c0..c0+15 (ld=64)
__device__ __forceinline__ void wfrag(const float* __restrict__ W, int nrows, int k0,
                                      int c0, int lane, i32x4& fh, i32x4& fl) {
  const int kb = k0 + ((lane >> 4) << 3);
  const int n = c0 + (lane & 15);
  float x[8];
#pragma unroll
  for (int j = 0; j < 8; ++j) {
    const int k = kb + j;
    x[j] = (k < nrows) ? W[k * 64 + n] : 0.f;
  }
  split8(x, fh, fl);
}

// ---------------- init / small kernels ----------------
__global__ __launch_bounds__(256) void k_init_h(const int* __restrict__ nt,
                                                const float* __restrict__ emb,
                                                float* __restrict__ h,
                                                unsigned short* __restrict__ hpk) {
  int idx = blockIdx.x * 256 + threadIdx.x;
  if (idx < NN * 64) {
    const int node = idx >> 6, c = idx & 63;
    const float v = emb[nt[node] * 64 + c];
    h[idx] = v;
    const unsigned hb = f2u(v) & 0xffff0000u;
    const float lo = v - __uint_as_float(hb);
    hpk[node * 128 + c] = (unsigned short)(hb >> 16);
    hpk[node * 128 + 64 + c] = (unsigned short)(f2u(lo) >> 16);
  }
}

__global__ __launch_bounds__(256) void k_prep(const float* __restrict__ pos_in,
                                              float* __restrict__ pos,
                                              float* __restrict__ deg,
                                              float* __restrict__ g,
                                              float* __restrict__ gcnt) {
  int idx = blockIdx.x * 256 + threadIdx.x;
  if (idx < NN * 3) pos[idx] = pos_in[idx];
  if (idx < NN) deg[idx] = 0.f;
  if (idx < NG * 64) g[idx] = 0.f;
  if (idx < NG) gcnt[idx] = 0.f;
}

__global__ __launch_bounds__(256) void k_hist(const int* __restrict__ ei,
                                              float* __restrict__ deg) {
  int e = blockIdx.x * 256 + threadIdx.x;
  if (e < NE) atomicAdd(&deg[ei[NE + e]], 1.f);
}

__global__ __launch_bounds__(256) void k_cnt(const int* __restrict__ batch,
                                             float* __restrict__ deg,
                                             float* __restrict__ gcnt) {
  int i = blockIdx.x * 256 + threadIdx.x;
  if (i < NN) {
    deg[i] = fmaxf(deg[i], 1.f);
    atomicAdd(&gcnt[batch[i]], 1.f);
  }
}

__global__ __launch_bounds__(256) void k_zero(float* __restrict__ agg,
                                              float* __restrict__ posd) {
  int idx = blockIdx.x * 256 + threadIdx.x;
  if (idx < NN * 64) agg[idx] = 0.f;
  else if (idx < NN * 64 + NN * 3) posd[idx - NN * 64] = 0.f;
}

__global__ __launch_bounds__(256) void k_pos(float* __restrict__ pos,
                                             const float* __restrict__ posd,
                                             const float* __restrict__ deg) {
  int idx = blockIdx.x * 256 + threadIdx.x;
  if (idx < NN * 3) pos[idx] += posd[idx] / deg[idx / 3];
}

// run-length pooled over sorted batch: ~1 atomic per 16 nodes per lane
__global__ __launch_bounds__(256) void k_pool(const float* __restrict__ h,
                                              const int* __restrict__ batch,
                                              float* __restrict__ g) {
  const int lane = threadIdx.x & 63;
  const int wid = (blockIdx.x * 256 + threadIdx.x) >> 6;
  const int nw = (gridDim.x * 256) >> 6;
  for (int n0 = wid * 16; n0 < NN; n0 += nw * 16) {
    float acc = 0.f;
    int curb = batch[n0];
#pragma unroll
    for (int i = 0; i < 16; ++i) {
      const int b = batch[n0 + i];
      const float v = h[(size_t)(n0 + i) * 64 + lane];
      if (b != curb) {
        atomicAdd(&g[curb * 64 + lane], acc);
        acc = 0.f;
        curb = b;
      }
      acc += v;
    }
    atomicAdd(&g[curb * 64 + lane], acc);
  }
}

// ---------------- edge message kernel ----------------
// 4 waves; 32 edges/iter (tiles A,B); wave w owns cols [16w,16w+16).
// h pre-quantized (hpk: bf16 hi|lo) -> GEMV1 A-frags are direct 16B loads.
// LDS m1/mm: plain bf16 hi/lo matrices, XOR-swizzled ((row&7)<<4) -> readers
// ds_read_b128 direct frags, writers pack col-pairs via shfl_xor+perm.
// 2 barriers/iter; posd handled by distributed per-wave partial atomics.
__global__ __launch_bounds__(256, 3) void k_edge(
    const unsigned short* __restrict__ hpk, const float* __restrict__ pos,
    const int* __restrict__ ei, const float* __restrict__ eattr,
    const float* __restrict__ W1, const float* __restrict__ B1,
    const float* __restrict__ W2, const float* __restrict__ B2,
    const float* __restrict__ C1, const float* __restrict__ CB1,
    const float* __restrict__ C2, const float* __restrict__ CB2,
    float* __restrict__ agg, float* __restrict__ posd) {
  __shared__ unsigned bm1[2 * 1024];  // [tile][16 rows][128B hi | 128B lo]
  __shared__ unsigned bmm[2 * 1024];
  __shared__ float relbuf[2][2][3][16];  // [parity][tile][coord][edge]

  const int lane = threadIdx.x & 63;
  const int w = threadIdx.x >> 6;
  const int m = lane & 15;
  const int quad = lane >> 4;
  const int col = 16 * w + m;

  char* m1A = (char*)&bm1[0];
  char* m1B = m1A + 4096;
  char* mmA = (char*)&bmm[0];
  char* mmB = mmA + 4096;
  const char* hB = (const char*)hpk;

  // register-resident weight fragments for this wave's n-slice
  i32x4 w1h[5], w1l[5], w2h[2], w2l[2], c1h[2], c1l[2];
#pragma unroll
  for (int s = 0; s < 5; ++s) wfrag(W1, 133, 32 * s, 16 * w, lane, w1h[s], w1l[s]);
#pragma unroll
  for (int s = 0; s < 2; ++s) wfrag(W2, 64, 32 * s, 16 * w, lane, w2h[s], w2l[s]);
#pragma unroll
  for (int s = 0; s < 2; ++s) wfrag(C1, 64, 32 * s, 16 * w, lane, c1h[s], c1l[s]);

  const float eb1v = B1[col], eb2v = B2[col], cb1v = CB1[col];
  const float cw2v = C2[col], cb2v = CB2[0];

  const int npair = NE / 32;
  int esA = 0, edA = 0, esB = 0, edB = 0;
  if ((int)blockIdx.x < npair) {
    const int b = blockIdx.x * 32 + m;
    esA = ei[b]; edA = ei[NE + b]; esB = ei[b + 16]; edB = ei[NE + b + 16];
  }

  int pp = 0;
  const int wrow_off = 32 * w + 2 * (m & ~1);  // byte-in-halfrow for col pair

  for (int g = blockIdx.x; g < npair; g += gridDim.x) {
    const int e0 = g * 32;
    const int cesA = esA, cedA = edA, cesB = esB, cedB = edB;
    const int g2 = g + gridDim.x;
    if (g2 < npair) {
      const int b = g2 * 32 + m;
      esA = ei[b]; edA = ei[NE + b]; esB = ei[b + 16]; edB = ei[NE + b + 16];
    }

    // ---- phase A: gathers (frag-ready), tail data, rel staging ----
    i32x4 fha[4], fla[4], fhb[4], flb[4];
#pragma unroll
    for (int s = 0; s < 4; ++s) {
      const unsigned node = (unsigned)(s < 2 ? cedA : cesA);
      const unsigned off = node * 256u + (unsigned)((s & 1) * 64 + quad * 16);
      fha[s] = *(const i32x4*)(hB + off);
      fla[s] = *(const i32x4*)(hB + off + 128);
    }
#pragma unroll
    for (int s = 0; s < 4; ++s) {
      const unsigned node = (unsigned)(s < 2 ? cedB : cesB);
      const unsigned off = node * 256u + (unsigned)((s & 1) * 64 + quad * 16);
      fhb[s] = *(const i32x4*)(hB + off);
      flb[s] = *(const i32x4*)(hB + off + 128);
    }

    float d2A = 0.f, aA0 = 0.f, aA1 = 0.f, aA2 = 0.f, aA3 = 0.f;
    float d2B = 0.f, aB0 = 0.f, aB1 = 0.f, aB2 = 0.f, aB3 = 0.f;
    if (lane < 16) {
      const float rxA = pos[cedA * 3 + 0] - pos[cesA * 3 + 0];
      const float ryA = pos[cedA * 3 + 1] - pos[cesA * 3 + 1];
      const float rzA = pos[cedA * 3 + 2] - pos[cesA * 3 + 2];
      d2A = rxA * rxA + ryA * ryA + rzA * rzA;
      const float4 ea = *(const float4*)(eattr + 4 * (e0 + lane));
      aA0 = ea.x; aA1 = ea.y; aA2 = ea.z; aA3 = ea.w;
      const float rxB = pos[cedB * 3 + 0] - pos[cesB * 3 + 0];
      const float ryB = pos[cedB * 3 + 1] - pos[cesB * 3 + 1];
      const float rzB = pos[cedB * 3 + 2] - pos[cesB * 3 + 2];
      d2B = rxB * rxB + ryB * ryB + rzB * rzB;
      const float4 eb = *(const float4*)(eattr + 4 * (e0 + 16 + lane));
      aB0 = eb.x; aB1 = eb.y; aB2 = eb.z; aB3 = eb.w;
      relbuf[pp][0][0][lane] = rxA;
      relbuf[pp][0][1][lane] = ryA;
      relbuf[pp][0][2][lane] = rzA;
      relbuf[pp][1][0][lane] = rxB;
      relbuf[pp][1][1][lane] = ryB;
      relbuf[pp][1][2][lane] = rzB;
    }

    // ---- phase B: GEMV1 m_in[16x160] @ W1[160x64] ----
    f32x4 aP = {eb1v, eb1v, eb1v, eb1v}, aQ = {0.f, 0.f, 0.f, 0.f};
    f32x4 bP = {eb1v, eb1v, eb1v, eb1v}, bQ = {0.f, 0.f, 0.f, 0.f};
#pragma unroll
    for (int s = 0; s < 4; ++s) {
      aP = mfma16(fha[s], w1h[s], aP);
      aQ = mfma16(fha[s], w1l[s], aQ);
      aQ = mfma16(fla[s], w1h[s], aQ);
    }
    {
      float x[8] = {d2A, aA0, aA1, aA2, aA3, 0.f, 0.f, 0.f};
      i32x4 th, tl;
      split8(x, th, tl);
      aP = mfma16(th, w1h[4], aP);
      aQ = mfma16(th, w1l[4], aQ);
      aQ = mfma16(tl, w1h[4], aQ);
    }
#pragma unroll
    for (int s = 0; s < 4; ++s) {
      bP = mfma16(fhb[s], w1h[s], bP);
      bQ = mfma16(fhb[s], w1l[s], bQ);
      bQ = mfma16(flb[s], w1h[s], bQ);
    }
    {
      float x[8] = {d2B, aB0, aB1, aB2, aB3, 0.f, 0.f, 0.f};
      i32x4 th, tl;
      split8(x, th, tl);
      bP = mfma16(th, w1h[4], bP);
      bQ = mfma16(th, w1l[4], bQ);
      bQ = mfma16(tl, w1h[4], bQ);
    }
#pragma unroll
    for (int r = 0; r < 4; ++r) {
      const float vA = silu_f(aP[r] + aQ[r]);
      const float vB = silu_f(bP[r] + bQ[r]);
      const float pA_ = __shfl_xor(vA, 1, 64);
      const float pB_ = __shfl_xor(vB, 1, 64);
      const int row = quad * 4 + r;
      const int off = row * 256 + (wrow_off ^ ((row & 7) << 4));
      if (!(m & 1)) {
        *(unsigned*)(m1A + off) = pk_hi(vA, pA_);
        *(unsigned*)(m1A + off + 128) = pk_hi(vA - hi_part(vA), pA_ - hi_part(pA_));
        *(unsigned*)(m1B + off) = pk_hi(vB, pB_);
        *(unsigned*)(m1B + off + 128) = pk_hi(vB - hi_part(vB), pB_ - hi_part(pB_));
      }
    }
    __syncthreads();

    // ---- phase C: GEMV2 m1[16x64] @ W2[64x64] ----
    f32x4 pA = {eb2v, eb2v, eb2v, eb2v}, qA = {0.f, 0.f, 0.f, 0.f};
    f32x4 pB = {eb2v, eb2v, eb2v, eb2v}, qB = {0.f, 0.f, 0.f, 0.f};
#pragma unroll
    for (int s = 0; s < 2; ++s) {
      const int roff = m * 256 + ((s * 64 + quad * 16) ^ ((m & 7) << 4));
      const i32x4 ahA = *(const i32x4*)(m1A + roff);
      const i32x4 alA = *(const i32x4*)(m1A + roff + 128);
      const i32x4 ahB = *(const i32x4*)(m1B + roff);
      const i32x4 alB = *(const i32x4*)(m1B + roff + 128);
      pA = mfma16(ahA, w2h[s], pA);
      qA = mfma16(ahA, w2l[s], qA);
      qA = mfma16(alA, w2h[s], qA);
      pB = mfma16(ahB, w2h[s], pB);
      qB = mfma16(ahB, w2l[s], qB);
      qB = mfma16(alB, w2h[s], qB);
    }
    float mmvA[4], mmvB[4];
#pragma unroll
    for (int r = 0; r < 4; ++r) {
      mmvA[r] = silu_f(pA[r] + qA[r]);
      mmvB[r] = silu_f(pB[r] + qB[r]);
      const float pA_ = __shfl_xor(mmvA[r], 1, 64);
      const float pB_ = __shfl_xor(mmvB[r], 1, 64);
      const int row = quad * 4 + r;
      const int off = row * 256 + (wrow_off ^ ((row & 7) << 4));
      if (!(m & 1)) {
        *(unsigned*)(mmA + off) = pk_hi(mmvA[r], pA_);
        *(unsigned*)(mmA + off + 128) = pk_hi(mmvA[r] - hi_part(mmvA[r]), pA_ - hi_part(pA_));
        *(unsigned*)(mmB + off) = pk_hi(mmvB[r], pB_);
        *(unsigned*)(mmB + off + 128) = pk_hi(mmvB[r] - hi_part(mmvB[r]), pB_ - hi_part(pB_));
      }
    }
    __syncthreads();

    // ---- phase D: coord MLP + all global atomics ----
    f32x4 uA = {cb1v, cb1v, cb1v, cb1v}, vA4 = {0.f, 0.f, 0.f, 0.f};
    f32x4 uB = {cb1v, cb1v, cb1v, cb1v}, vB4 = {0.f, 0.f, 0.f, 0.f};
#pragma unroll
    for (int s = 0; s < 2; ++s) {
      const int roff = m * 256 + ((s * 64 + quad * 16) ^ ((m & 7) << 4));
      const i32x4 ahA = *(const i32x4*)(mmA + roff);
      const i32x4 alA = *(const i32x4*)(mmA + roff + 128);
      const i32x4 ahB = *(const i32x4*)(mmB + roff);
      const i32x4 alB = *(const i32x4*)(mmB + roff + 128);
      uA = mfma16(ahA, c1h[s], uA);
      vA4 = mfma16(ahA, c1l[s], vA4);
      vA4 = mfma16(alA, c1h[s], vA4);
      uB = mfma16(ahB, c1h[s], uB);
      vB4 = mfma16(ahB, c1l[s], vB4);
      vB4 = mfma16(alB, c1h[s], vB4);
    }
    float trA[4], trB[4];
#pragma unroll
    for (int r = 0; r < 4; ++r) {
      trA[r] = silu_f(uA[r] + vA4[r]) * cw2v;
      trB[r] = silu_f(uB[r] + vB4[r]) * cw2v;
    }
#pragma unroll
    for (int mask = 1; mask < 16; mask <<= 1)
#pragma unroll
      for (int r = 0; r < 4; ++r) {
        trA[r] += __shfl_xor(trA[r], mask, 64);
        trB[r] += __shfl_xor(trB[r], mask, 64);
      }
    // distributed posd atomics: lane (m>>2 = r, m&3 = coord), per quad
    {
      const int rr = m >> 2, cc = m & 3;
      const int e = quad * 4 + rr;
      const int dA_ = __shfl(cedA, e, 64);
      const int dB_ = __shfl(cedB, e, 64);
      float tA = (rr & 2) ? ((rr & 1) ? trA[3] : trA[2])
                          : ((rr & 1) ? trA[1] : trA[0]);
      float tB = (rr & 2) ? ((rr & 1) ? trB[3] : trB[2])
                          : ((rr & 1) ? trB[1] : trB[0]);
      if (w == 0) { tA += cb2v; tB += cb2v; }
      if (cc < 3) {
        const float relA = relbuf[pp][0][cc][e];
        const float relB = relbuf[pp][1][cc][e];
        atomicAdd(&posd[dA_ * 3 + cc], relA * tA);
        atomicAdd(&posd[dB_ * 3 + cc], relB * tB);
      }
    }
#pragma unroll
    for (int r = 0; r < 4; ++r) {
      const int rdA = __shfl(cedA, quad * 4 + r, 64);
      atomicAdd(&agg[(size_t)rdA * 64 + col], mmvA[r]);
    }
#pragma unroll
    for (int r = 0; r < 4; ++r) {
      const int rdB = __shfl(cedB, quad * 4 + r, 64);
      atomicAdd(&agg[(size_t)rdB * 64 + col], mmvB[r]);
    }
    pp ^= 1;
  }
}

// ---------------- node update kernel (8-node batch per wave) ----------------
__global__ __launch_bounds__(256) void k_node(
    float* __restrict__ h, unsigned short* __restrict__ hpk,
    const float* __restrict__ agg,
    const float* __restrict__ W1, const float* __restrict__ B1,
    const float* __restrict__ W2, const float* __restrict__ B2) {
  __shared__ float sW1[128 * 64];
  __shared__ float sW2[64 * 64];
  for (int i = threadIdx.x; i < 128 * 64; i += 256) sW1[i] = W1[i];
  for (int i = threadIdx.x; i < 64 * 64; i += 256) sW2[i] = W2[i];
  __syncthreads();
  const int lane = threadIdx.x & 63;
  const float nb1 = B1[lane], nb2 = B2[lane];
  const int wid = (blockIdx.x * 256 + threadIdx.x) >> 6;
  const int nw = (gridDim.x * 256) >> 6;
  for (int n0 = wid * 8; n0 < NN; n0 += nw * 8) {
    float hj[8], aj[8], a1[8];
#pragma unroll
    for (int i = 0; i < 8; ++i) {
      hj[i] = h[(size_t)(n0 + i) * 64 + lane];
      aj[i] = agg[(size_t)(n0 + i) * 64 + lane];
      a1[i] = nb1;
    }
#pragma unroll
    for (int k = 0; k < 64; ++k) {
      const float wv = sW1[k * 64 + lane];
#pragma unroll
      for (int i = 0; i < 8; ++i) a1[i] += rdl(hj[i], k) * wv;
    }
#pragma unroll
    for (int k = 0; k < 64; ++k) {
      const float wv = sW1[(64 + k) * 64 + lane];
#pragma unroll
      for (int i = 0; i < 8; ++i) a1[i] += rdl(aj[i], k) * wv;
    }
    float u[8], a2[8];
#pragma unroll
    for (int i = 0; i < 8; ++i) { u[i] = silu_f(a1[i]); a2[i] = nb2; }
#pragma unroll
    for (int k = 0; k < 64; ++k) {
      const float wv = sW2[k * 64 + lane];
#pragma unroll
      for (int i = 0; i < 8; ++i) a2[i] += rdl(u[i], k) * wv;
    }
#pragma unroll
    for (int i = 0; i < 8; ++i) {
      const float hn = hj[i] + a2[i];
      h[(size_t)(n0 + i) * 64 + lane] = hn;
      const unsigned hb = f2u(hn) & 0xffff0000u;
      const float lo = hn - __uint_as_float(hb);
      hpk[(size_t)(n0 + i) * 128 + lane] = (unsigned short)(hb >> 16);
      hpk[(size_t)(n0 + i) * 128 + 64 + lane] = (unsigned short)(f2u(lo) >> 16);
    }
  }
}

// ---------------- pooled head: q-circuit + MLP ----------------
__global__ __launch_bounds__(256) void k_final(
    const float* __restrict__ g, const float* __restrict__ gcnt,
    const float* __restrict__ prew, const float* __restrict__ preb,
    const float* __restrict__ qw, const float* __restrict__ pw1,
    const float* __restrict__ pb1, const float* __restrict__ pw2,
    const float* __restrict__ pb2, float* __restrict__ out) {
  const int lane = threadIdx.x & 63;
  const int gid = (blockIdx.x * 256 + threadIdx.x) >> 6;
  if (gid >= NG) return;
  const float cnt = fmaxf(gcnt[gid], 1.f);
  const float gv = g[gid * 64 + lane] / cnt;
  float qin[4];
#pragma unroll
  for (int q = 0; q < 4; ++q)
    qin[q] = wave_sum(gv * prew[lane * 4 + q]) + preb[q];
  float sr[16], si[16];
#pragma unroll
  for (int i = 0; i < 16; ++i) { sr[i] = 0.f; si[i] = 0.f; }
  sr[0] = 1.f;
#pragma unroll
  for (int q = 0; q < 4; ++q) {  // RX(qin[q])
    const int mask = 8 >> q;
    float s, c;
    __sincosf(qin[q] * 0.5f, &s, &c);
#pragma unroll
    for (int i = 0; i < 16; ++i)
      if (!(i & mask)) {
        const int j = i | mask;
        const float ar = sr[i], ai = si[i], br = sr[j], bi = si[j];
        sr[i] = c * ar + s * bi; si[i] = c * ai - s * br;
        sr[j] = c * br + s * ai; si[j] = c * bi - s * ar;
      }
  }
#pragma unroll
  for (int l = 0; l < 2; ++l) {
#pragma unroll
    for (int q = 0; q < 4; ++q) {  // RY(qw[l][q])
      const int mask = 8 >> q;
      float s, c;
      __sincosf(qw[l * 4 + q] * 0.5f, &s, &c);
#pragma unroll
      for (int i = 0; i < 16; ++i)
        if (!(i & mask)) {
          const int j = i | mask;
          const float ar = sr[i], ai = si[i], br = sr[j], bi = si[j];
          sr[i] = c * ar - s * br; si[i] = c * ai - s * bi;
          sr[j] = s * ar + c * br; si[j] = s * ai + c * bi;
        }
    }
#pragma unroll
    for (int q = 0; q < 4; ++q) {  // CNOT q -> (q+1)%4
      const int mc = 8 >> q;
      const int mt = 8 >> ((q + 1) & 3);
#pragma unroll
      for (int i = 0; i < 16; ++i)
        if ((i & mc) && !(i & mt)) {
          const int j = i | mt;
          float t = sr[i]; sr[i] = sr[j]; sr[j] = t;
          t = si[i]; si[i] = si[j]; si[j] = t;
        }
    }
  }
  float qo[4] = {0.f, 0.f, 0.f, 0.f};
#pragma unroll
  for (int i = 0; i < 16; ++i) {
    const float p = sr[i] * sr[i] + si[i] * si[i];
#pragma unroll
    for (int q = 0; q < 4; ++q) qo[q] += ((i >> (3 - q)) & 1) ? -p : p;
  }
  float t = pb1[lane];
#pragma unroll
  for (int q = 0; q < 4; ++q) t += qo[q] * pw1[q * 64 + lane];
  const float r = wave_sum(silu_f(t) * pw2[lane]);
  if (lane == 0) out[gid] = r + pb2[0];
}

extern "C" void kernel_launch(void* const* d_in, const int* in_sizes, int n_in,
                              void* d_out, int out_size, void* d_ws, size_t ws_size,
                              hipStream_t stream) {
  (void)in_sizes; (void)n_in; (void)out_size; (void)ws_size;
  const int*   nt    = (const int*)d_in[0];
  const float* pos0  = (const float*)d_in[1];
  const int*   ei    = (const int*)d_in[2];
  const float* eattr = (const float*)d_in[3];
  const int*   batch = (const int*)d_in[4];
  const float* emb   = (const float*)d_in[5];
  const float* ew1   = (const float*)d_in[6];
  const float* eb1   = (const float*)d_in[7];
  const float* ew2   = (const float*)d_in[8];
  const float* eb2   = (const float*)d_in[9];
  const float* cw1   = (const float*)d_in[10];
  const float* cb1   = (const float*)d_in[11];
  const float* cw2   = (const float*)d_in[12];
  const float* cb2   = (const float*)d_in[13];
  const float* nw1   = (const float*)d_in[14];
  const float* nb1   = (const float*)d_in[15];
  const float* nw2   = (const float*)d_in[16];
  const float* nb2   = (const float*)d_in[17];
  const float* prew  = (const float*)d_in[18];
  const float* preb  = (const float*)d_in[19];
  const float* qw    = (const float*)d_in[20];
  const float* pw1   = (const float*)d_in[21];
  const float* pb1   = (const float*)d_in[22];
  const float* pw2   = (const float*)d_in[23];
  const float* pb2   = (const float*)d_in[24];
  float* out = (float*)d_out;

  float* ws   = (float*)d_ws;
  float* h    = ws;               // NN*64
  float* pos  = h + NN * 64;      // NN*3
  float* posd = pos + NN * 3;     // NN*3
  float* agg  = posd + NN * 3;    // NN*64
  float* deg  = agg + NN * 64;    // NN
  float* g    = deg + NN;         // NG*64
  float* gcnt = g + NG * 64;      // NG
  unsigned short* hpk = (unsigned short*)(gcnt + NG);  // NN*128 bf16 (hi|lo)

  k_init_h<<<(NN * 64 + 255) / 256, 256, 0, stream>>>(nt, emb, h, hpk);
  k_prep<<<(NN * 3 + 255) / 256, 256, 0, stream>>>(pos0, pos, deg, g, gcnt);
  k_hist<<<(NE + 255) / 256, 256, 0, stream>>>(ei, deg);
  k_cnt<<<(NN + 255) / 256, 256, 0, stream>>>(batch, deg, gcnt);
  for (int l = 0; l < NL; ++l) {
    k_zero<<<(NN * 67 + 255) / 256, 256, 0, stream>>>(agg, posd);
    k_edge<<<2048, 256, 0, stream>>>(hpk, pos, ei, eattr,
        ew1 + l * 133 * 64, eb1 + l * 64, ew2 + l * 64 * 64, eb2 + l * 64,
        cw1 + l * 64 * 64, cb1 + l * 64, cw2 + l * 64, cb2 + l, agg, posd);
    k_pos<<<(NN * 3 + 255) / 256, 256, 0, stream>>>(pos, posd, deg);
    k_node<<<512, 256, 0, stream>>>(h, hpk, agg, nw1 + l * 128 * 64, nb1 + l * 64,
                                    nw2 + l * 64 * 64, nb2 + l * 64);
  }
  k_pool<<<800, 256, 0, stream>>>(h, batch, g);
  k_final<<<(NG * 64 + 255) / 256, 256, 0, stream>>>(g, gcnt, prew, preb, qw,
                                                     pw1, pb1, pw2, pb2, out);
}

// Round 3
// 1708.683 us; speedup vs baseline: 1.1544x; 1.1544x over previous
//
#include <hip/hip_runtime.h>

#define NN 50000
#define NE 800000
#define NG 128
#define NL 3

typedef __attribute__((ext_vector_type(8))) short short8;
typedef __attribute__((ext_vector_type(4))) float f32x4;
typedef __attribute__((ext_vector_type(4))) int i32x4;

union FragU { i32x4 i; short8 s; };

__device__ __forceinline__ float silu_f(float x) { return x / (1.f + __expf(-x)); }
__device__ __forceinline__ float rdl(float v, int l) {
  return __int_as_float(__builtin_amdgcn_readlane(__float_as_int(v), l));
}
__device__ __forceinline__ float wave_sum(float v) {
#pragma unroll
  for (int m = 1; m < 64; m <<= 1) v += __shfl_xor(v, m, 64);
  return v;
}

__device__ __forceinline__ unsigned f2u(float x) { return __float_as_uint(x); }
__device__ __forceinline__ float hi_part(float x) {
  return __uint_as_float(f2u(x) & 0xffff0000u);
}
// pack two fp32 -> (bf16,bf16) dword via truncation; e0 in low half
__device__ __forceinline__ unsigned pk_hi(float e0, float e1) {
  return __builtin_amdgcn_perm(f2u(e1), f2u(e0), 0x07060302u);
}

__device__ __forceinline__ f32x4 mfma16(i32x4 a, i32x4 b, f32x4 c) {
  FragU ua, ub; ua.i = a; ub.i = b;
  return __builtin_amdgcn_mfma_f32_16x16x32_bf16(ua.s, ub.s, c, 0, 0, 0);
}

// split 8 fp32 into hi/lo bf16x8 fragments (element order: k ascending)
__device__ __forceinline__ void split8(const float* x, i32x4& fh, i32x4& fl) {
#pragma unroll
  for (int i = 0; i < 4; ++i) {
    const float a = x[2 * i], b = x[2 * i + 1];
    fh[i] = (int)pk_hi(a, b);
    fl[i] = (int)pk_hi(a - hi_part(a), b - hi_part(b));
  }
}

// B-frag (hi/lo) for W[k][n]: rows k0..k0+31 (no bounds check), col n (ld=64)
__device__ __forceinline__ void wfrag_nb(const float* __restrict__ W, int k0,
                                         int n, int lane, i32x4& fh, i32x4& fl) {
  const int kb = k0 + ((lane >> 4) << 3);
  float x[8];
#pragma unroll
  for (int j = 0; j < 8; ++j) x[j] = W[(kb + j) * 64 + n];
  split8(x, fh, fl);
}

// ---------------- init / small kernels ----------------
__global__ __launch_bounds__(256) void k_init_h(const int* __restrict__ nt,
                                                const float* __restrict__ emb,
                                                float* __restrict__ h,
                                                unsigned short* __restrict__ hpk) {
  int idx = blockIdx.x * 256 + threadIdx.x;
  if (idx < NN * 64) {
    const int node = idx >> 6, c = idx & 63;
    const float v = emb[nt[node] * 64 + c];
    h[idx] = v;
    const unsigned hb = f2u(v) & 0xffff0000u;
    const float lo = v - __uint_as_float(hb);
    hpk[node * 128 + c] = (unsigned short)(hb >> 16);
    hpk[node * 128 + 64 + c] = (unsigned short)(f2u(lo) >> 16);
  }
}

__global__ __launch_bounds__(256) void k_prep(const float* __restrict__ pos_in,
                                              float* __restrict__ pos,
                                              float* __restrict__ deg,
                                              float* __restrict__ g,
                                              float* __restrict__ gcnt) {
  int idx = blockIdx.x * 256 + threadIdx.x;
  if (idx < NN * 3) pos[idx] = pos_in[idx];
  if (idx < NN) deg[idx] = 0.f;
  if (idx < NG * 64) g[idx] = 0.f;
  if (idx < NG) gcnt[idx] = 0.f;
}

__global__ __launch_bounds__(256) void k_hist(const int* __restrict__ ei,
                                              float* __restrict__ deg) {
  int e = blockIdx.x * 256 + threadIdx.x;
  if (e < NE) atomicAdd(&deg[ei[NE + e]], 1.f);
}

__global__ __launch_bounds__(256) void k_cnt(const int* __restrict__ batch,
                                             float* __restrict__ deg,
                                             float* __restrict__ gcnt) {
  int i = blockIdx.x * 256 + threadIdx.x;
  if (i < NN) {
    deg[i] = fmaxf(deg[i], 1.f);
    atomicAdd(&gcnt[batch[i]], 1.f);
  }
}

__global__ __launch_bounds__(256) void k_zero(float* __restrict__ agg,
                                              float* __restrict__ posd) {
  int idx = blockIdx.x * 256 + threadIdx.x;
  if (idx < NN * 64) agg[idx] = 0.f;
  else if (idx < NN * 64 + NN * 3) posd[idx - NN * 64] = 0.f;
}

__global__ __launch_bounds__(256) void k_pos(float* __restrict__ pos,
                                             const float* __restrict__ posd,
                                             const float* __restrict__ deg) {
  int idx = blockIdx.x * 256 + threadIdx.x;
  if (idx < NN * 3) pos[idx] += posd[idx] / deg[idx / 3];
}

// run-length pooled over sorted batch
__global__ __launch_bounds__(256) void k_pool(const float* __restrict__ h,
                                              const int* __restrict__ batch,
                                              float* __restrict__ g) {
  const int lane = threadIdx.x & 63;
  const int wid = (blockIdx.x * 256 + threadIdx.x) >> 6;
  const int nw = (gridDim.x * 256) >> 6;
  for (int n0 = wid * 16; n0 < NN; n0 += nw * 16) {
    float acc = 0.f;
    int curb = batch[n0];
#pragma unroll
    for (int i = 0; i < 16; ++i) {
      const int b = batch[n0 + i];
      const float v = h[(size_t)(n0 + i) * 64 + lane];
      if (b != curb) {
        atomicAdd(&g[curb * 64 + lane], acc);
        acc = 0.f;
        curb = b;
      }
      acc += v;
    }
    atomicAdd(&g[curb * 64 + lane], acc);
  }
}

// ---------------- edge message kernel ----------------
// 4 waves; 32 edges/iter (tiles A,B); wave w owns cols [16w,16w+16).
// Weight fragments staged ONCE into LDS in final MFMA-frag layout (each
// thread owns its 16B slot; in-loop access = 1 ds_read_b128, 0 VALU) --
// this removes the wfrag rematerialization that dominated R0-R2.
// W1 tail rows 128..132 handled as exact-fp32 rank-1 VALU update.
// LDS = 64KB weight frags + 16KB m1/mm = 81920B exactly -> 2 blocks/CU.
__global__ __launch_bounds__(256, 2) void k_edge(
    const unsigned short* __restrict__ hpk, const float* __restrict__ pos,
    const int* __restrict__ ei, const float* __restrict__ eattr,
    const float* __restrict__ W1, const float* __restrict__ B1,
    const float* __restrict__ W2, const float* __restrict__ B2,
    const float* __restrict__ C1, const float* __restrict__ CB1,
    const float* __restrict__ C2, const float* __restrict__ CB2,
    float* __restrict__ agg, float* __restrict__ posd) {
  __shared__ i32x4 smem[5120];  // 81920 B exactly
  // [0,1024)  w1h frags (s*256+tid, s=0..3)   [1024,2048) w1l
  // [2048,2560) w2h (s=0..1)                  [2560,3072) w2l
  // [3072,3584) c1h                           [3584,4096) c1l
  // [4096,4608) bm1 (tile A @+0, B @+4096B)   [4608,5120) bmm

  const int tid = threadIdx.x;
  const int lane = tid & 63;
  const int w = tid >> 6;
  const int m = lane & 15;
  const int quad = lane >> 4;
  const int col = 16 * w + m;

  char* bm1 = (char*)&smem[4096];
  char* bmm = (char*)&smem[4608];
  const char* hB = (const char*)hpk;

  // ---- one-time: build this thread's weight frags into LDS ----
  {
    i32x4 fh, fl;
#pragma unroll
    for (int s = 0; s < 4; ++s) {
      wfrag_nb(W1, 32 * s, col, lane, fh, fl);
      smem[s * 256 + tid] = fh;
      smem[1024 + s * 256 + tid] = fl;
    }
#pragma unroll
    for (int s = 0; s < 2; ++s) {
      wfrag_nb(W2, 32 * s, col, lane, fh, fl);
      smem[2048 + s * 256 + tid] = fh;
      smem[2560 + s * 256 + tid] = fl;
    }
#pragma unroll
    for (int s = 0; s < 2; ++s) {
      wfrag_nb(C1, 32 * s, col, lane, fh, fl);
      smem[3072 + s * 256 + tid] = fh;
      smem[3584 + s * 256 + tid] = fl;
    }
  }
  // W1 tail rows (fp32 rank-1 path)
  float w1t[5];
#pragma unroll
  for (int t = 0; t < 5; ++t) w1t[t] = W1[(128 + t) * 64 + col];

  const float eb1v = B1[col], eb2v = B2[col], cb1v = CB1[col];
  const float cw2v = C2[col], cb2v = CB2[0];

  const int npair = NE / 32;
  int esA = 0, edA = 0, esB = 0, edB = 0;
  if ((int)blockIdx.x < npair) {
    const int b = blockIdx.x * 32 + m;
    esA = ei[b]; edA = ei[NE + b]; esB = ei[b + 16]; edB = ei[NE + b + 16];
  }

  const int wrow_off = 32 * w + 2 * (m & ~1);  // byte-in-halfrow for col pair

  for (int g = blockIdx.x; g < npair; g += gridDim.x) {
    const int e0 = g * 32;
    const int cesA = esA, cedA = edA, cesB = esB, cedB = edB;
    const int g2 = g + gridDim.x;
    if (g2 < npair) {
      const int b = g2 * 32 + m;
      esA = ei[b]; edA = ei[NE + b]; esB = ei[b + 16]; edB = ei[NE + b + 16];
    }

    // ---- phase A: gathers (frag-ready) + per-edge tail data ----
    i32x4 fha[4], fla[4], fhb[4], flb[4];
#pragma unroll
    for (int s = 0; s < 4; ++s) {
      const unsigned node = (unsigned)(s < 2 ? cedA : cesA);
      const unsigned off = node * 256u + (unsigned)((s & 1) * 64 + quad * 16);
      fha[s] = *(const i32x4*)(hB + off);
      fla[s] = *(const i32x4*)(hB + off + 128);
    }
#pragma unroll
    for (int s = 0; s < 4; ++s) {
      const unsigned node = (unsigned)(s < 2 ? cedB : cesB);
      const unsigned off = node * 256u + (unsigned)((s & 1) * 64 + quad * 16);
      fhb[s] = *(const i32x4*)(hB + off);
      flb[s] = *(const i32x4*)(hB + off + 128);
    }

    float d2A = 0.f, aA0 = 0.f, aA1 = 0.f, aA2 = 0.f, aA3 = 0.f;
    float rxA = 0.f, ryA = 0.f, rzA = 0.f;
    float d2B = 0.f, aB0 = 0.f, aB1 = 0.f, aB2 = 0.f, aB3 = 0.f;
    float rxB = 0.f, ryB = 0.f, rzB = 0.f;
    if (lane < 16) {
      rxA = pos[cedA * 3 + 0] - pos[cesA * 3 + 0];
      ryA = pos[cedA * 3 + 1] - pos[cesA * 3 + 1];
      rzA = pos[cedA * 3 + 2] - pos[cesA * 3 + 2];
      d2A = rxA * rxA + ryA * ryA + rzA * rzA;
      const float4 ea = *(const float4*)(eattr + 4 * (e0 + lane));
      aA0 = ea.x; aA1 = ea.y; aA2 = ea.z; aA3 = ea.w;
      rxB = pos[cedB * 3 + 0] - pos[cesB * 3 + 0];
      ryB = pos[cedB * 3 + 1] - pos[cesB * 3 + 1];
      rzB = pos[cedB * 3 + 2] - pos[cesB * 3 + 2];
      d2B = rxB * rxB + ryB * ryB + rzB * rzB;
      const float4 eb = *(const float4*)(eattr + 4 * (e0 + 16 + lane));
      aB0 = eb.x; aB1 = eb.y; aB2 = eb.z; aB3 = eb.w;
    }

    // ---- phase B: GEMV1 m_in[16x160] @ W1[160x64] ----
    f32x4 aP = {eb1v, eb1v, eb1v, eb1v}, aQ = {0.f, 0.f, 0.f, 0.f};
    f32x4 bP = {eb1v, eb1v, eb1v, eb1v}, bQ = {0.f, 0.f, 0.f, 0.f};
#pragma unroll
    for (int s = 0; s < 4; ++s) {
      const i32x4 wh = smem[s * 256 + tid];
      const i32x4 wl = smem[1024 + s * 256 + tid];
      aP = mfma16(fha[s], wh, aP);
      aQ = mfma16(fha[s], wl, aQ);
      aQ = mfma16(fla[s], wh, aQ);
      bP = mfma16(fhb[s], wh, bP);
      bQ = mfma16(fhb[s], wl, bQ);
      bQ = mfma16(flb[s], wh, bQ);
    }
    // exact-fp32 tail: cols 128..132 = [d2, ea0..3]
#pragma unroll
    for (int r = 0; r < 4; ++r) {
      const int e = quad * 4 + r;
      aP[r] += __shfl(d2A, e, 64) * w1t[0] + __shfl(aA0, e, 64) * w1t[1] +
               __shfl(aA1, e, 64) * w1t[2] + __shfl(aA2, e, 64) * w1t[3] +
               __shfl(aA3, e, 64) * w1t[4];
      bP[r] += __shfl(d2B, e, 64) * w1t[0] + __shfl(aB0, e, 64) * w1t[1] +
               __shfl(aB1, e, 64) * w1t[2] + __shfl(aB2, e, 64) * w1t[3] +
               __shfl(aB3, e, 64) * w1t[4];
    }
#pragma unroll
    for (int r = 0; r < 4; ++r) {
      const float vA = silu_f(aP[r] + aQ[r]);
      const float vB = silu_f(bP[r] + bQ[r]);
      const float pA_ = __shfl_xor(vA, 1, 64);
      const float pB_ = __shfl_xor(vB, 1, 64);
      const int row = quad * 4 + r;
      const int off = row * 256 + (wrow_off ^ ((row & 7) << 4));
      if (!(m & 1)) {
        *(unsigned*)(bm1 + off) = pk_hi(vA, pA_);
        *(unsigned*)(bm1 + off + 128) = pk_hi(vA - hi_part(vA), pA_ - hi_part(pA_));
        *(unsigned*)(bm1 + 4096 + off) = pk_hi(vB, pB_);
        *(unsigned*)(bm1 + 4096 + off + 128) = pk_hi(vB - hi_part(vB), pB_ - hi_part(pB_));
      }
    }
    __syncthreads();

    // ---- phase C: GEMV2 m1[16x64] @ W2[64x64] ----
    f32x4 pA = {eb2v, eb2v, eb2v, eb2v}, qA = {0.f, 0.f, 0.f, 0.f};
    f32x4 pB = {eb2v, eb2v, eb2v, eb2v}, qB = {0.f, 0.f, 0.f, 0.f};
#pragma unroll
    for (int s = 0; s < 2; ++s) {
      const int roff = m * 256 + ((s * 64 + quad * 16) ^ ((m & 7) << 4));
      const i32x4 ahA = *(const i32x4*)(bm1 + roff);
      const i32x4 alA = *(const i32x4*)(bm1 + roff + 128);
      const i32x4 ahB = *(const i32x4*)(bm1 + 4096 + roff);
      const i32x4 alB = *(const i32x4*)(bm1 + 4096 + roff + 128);
      const i32x4 wh = smem[2048 + s * 256 + tid];
      const i32x4 wl = smem[2560 + s * 256 + tid];
      pA = mfma16(ahA, wh, pA);
      qA = mfma16(ahA, wl, qA);
      qA = mfma16(alA, wh, qA);
      pB = mfma16(ahB, wh, pB);
      qB = mfma16(ahB, wl, qB);
      qB = mfma16(alB, wh, qB);
    }
    float mmvA[4], mmvB[4];
#pragma unroll
    for (int r = 0; r < 4; ++r) {
      mmvA[r] = silu_f(pA[r] + qA[r]);
      mmvB[r] = silu_f(pB[r] + qB[r]);
      const float pA_ = __shfl_xor(mmvA[r], 1, 64);
      const float pB_ = __shfl_xor(mmvB[r], 1, 64);
      const int row = quad * 4 + r;
      const int off = row * 256 + (wrow_off ^ ((row & 7) << 4));
      if (!(m & 1)) {
        *(unsigned*)(bmm + off) = pk_hi(mmvA[r], pA_);
        *(unsigned*)(bmm + off + 128) = pk_hi(mmvA[r] - hi_part(mmvA[r]), pA_ - hi_part(pA_));
        *(unsigned*)(bmm + 4096 + off) = pk_hi(mmvB[r], pB_);
        *(unsigned*)(bmm + 4096 + off + 128) = pk_hi(mmvB[r] - hi_part(mmvB[r]), pB_ - hi_part(pB_));
      }
    }
    __syncthreads();

    // ---- phase D: coord MLP + all global atomics (drain overlaps next iter) ----
    f32x4 uA = {cb1v, cb1v, cb1v, cb1v}, vA4 = {0.f, 0.f, 0.f, 0.f};
    f32x4 uB = {cb1v, cb1v, cb1v, cb1v}, vB4 = {0.f, 0.f, 0.f, 0.f};
#pragma unroll
    for (int s = 0; s < 2; ++s) {
      const int roff = m * 256 + ((s * 64 + quad * 16) ^ ((m & 7) << 4));
      const i32x4 ahA = *(const i32x4*)(bmm + roff);
      const i32x4 alA = *(const i32x4*)(bmm + roff + 128);
      const i32x4 ahB = *(const i32x4*)(bmm + 4096 + roff);
      const i32x4 alB = *(const i32x4*)(bmm + 4096 + roff + 128);
      const i32x4 wh = smem[3072 + s * 256 + tid];
      const i32x4 wl = smem[3584 + s * 256 + tid];
      uA = mfma16(ahA, wh, uA);
      vA4 = mfma16(ahA, wl, vA4);
      vA4 = mfma16(alA, wh, vA4);
      uB = mfma16(ahB, wh, uB);
      vB4 = mfma16(ahB, wl, vB4);
      vB4 = mfma16(alB, wh, vB4);
    }
    float trA[4], trB[4];
#pragma unroll
    for (int r = 0; r < 4; ++r) {
      trA[r] = silu_f(uA[r] + vA4[r]) * cw2v;
      trB[r] = silu_f(uB[r] + vB4[r]) * cw2v;
    }
#pragma unroll
    for (int mask = 1; mask < 16; mask <<= 1)
#pragma unroll
      for (int r = 0; r < 4; ++r) {
        trA[r] += __shfl_xor(trA[r], mask, 64);
        trB[r] += __shfl_xor(trB[r], mask, 64);
      }
    // distributed posd atomics: lane (m>>2 = row, m&3 = coord), per quad
    {
      const int rr = m >> 2, cc = m & 3;
      const int e = quad * 4 + rr;
      const int dA_ = __shfl(cedA, e, 64);
      const int dB_ = __shfl(cedB, e, 64);
      const float axA = __shfl(rxA, e, 64), ayA = __shfl(ryA, e, 64), azA = __shfl(rzA, e, 64);
      const float axB = __shfl(rxB, e, 64), ayB = __shfl(ryB, e, 64), azB = __shfl(rzB, e, 64);
      float tA = (rr & 2) ? ((rr & 1) ? trA[3] : trA[2])
                          : ((rr & 1) ? trA[1] : trA[0]);
      float tB = (rr & 2) ? ((rr & 1) ? trB[3] : trB[2])
                          : ((rr & 1) ? trB[1] : trB[0]);
      if (w == 0) { tA += cb2v; tB += cb2v; }
      if (cc < 3) {
        const float relA = cc == 0 ? axA : (cc == 1 ? ayA : azA);
        const float relB = cc == 0 ? axB : (cc == 1 ? ayB : azB);
        atomicAdd(&posd[dA_ * 3 + cc], relA * tA);
        atomicAdd(&posd[dB_ * 3 + cc], relB * tB);
      }
    }
#pragma unroll
    for (int r = 0; r < 4; ++r) {
      const int rdA = __shfl(cedA, quad * 4 + r, 64);
      atomicAdd(&agg[(size_t)rdA * 64 + col], mmvA[r]);
    }
#pragma unroll
    for (int r = 0; r < 4; ++r) {
      const int rdB = __shfl(cedB, quad * 4 + r, 64);
      atomicAdd(&agg[(size_t)rdB * 64 + col], mmvB[r]);
    }
  }
}

// ---------------- node update kernel (8-node batch per wave) ----------------
__global__ __launch_bounds__(256) void k_node(
    float* __restrict__ h, unsigned short* __restrict__ hpk,
    const float* __restrict__ agg,
    const float* __restrict__ W1, const float* __restrict__ B1,
    const float* __restrict__ W2, const float* __restrict__ B2) {
  __shared__ float sW1[128 * 64];
  __shared__ float sW2[64 * 64];
  for (int i = threadIdx.x; i < 128 * 64; i += 256) sW1[i] = W1[i];
  for (int i = threadIdx.x; i < 64 * 64; i += 256) sW2[i] = W2[i];
  __syncthreads();
  const int lane = threadIdx.x & 63;
  const float nb1 = B1[lane], nb2 = B2[lane];
  const int wid = (blockIdx.x * 256 + threadIdx.x) >> 6;
  const int nw = (gridDim.x * 256) >> 6;
  for (int n0 = wid * 8; n0 < NN; n0 += nw * 8) {
    float hj[8], aj[8], a1[8];
#pragma unroll
    for (int i = 0; i < 8; ++i) {
      hj[i] = h[(size_t)(n0 + i) * 64 + lane];
      aj[i] = agg[(size_t)(n0 + i) * 64 + lane];
      a1[i] = nb1;
    }
#pragma unroll
    for (int k = 0; k < 64; ++k) {
      const float wv = sW1[k * 64 + lane];
#pragma unroll
      for (int i = 0; i < 8; ++i) a1[i] += rdl(hj[i], k) * wv;
    }
#pragma unroll
    for (int k = 0; k < 64; ++k) {
      const float wv = sW1[(64 + k) * 64 + lane];
#pragma unroll
      for (int i = 0; i < 8; ++i) a1[i] += rdl(aj[i], k) * wv;
    }
    float u[8], a2[8];
#pragma unroll
    for (int i = 0; i < 8; ++i) { u[i] = silu_f(a1[i]); a2[i] = nb2; }
#pragma unroll
    for (int k = 0; k < 64; ++k) {
      const float wv = sW2[k * 64 + lane];
#pragma unroll
      for (int i = 0; i < 8; ++i) a2[i] += rdl(u[i], k) * wv;
    }
#pragma unroll
    for (int i = 0; i < 8; ++i) {
      const float hn = hj[i] + a2[i];
      h[(size_t)(n0 + i) * 64 + lane] = hn;
      const unsigned hb = f2u(hn) & 0xffff0000u;
      const float lo = hn - __uint_as_float(hb);
      hpk[(size_t)(n0 + i) * 128 + lane] = (unsigned short)(hb >> 16);
      hpk[(size_t)(n0 + i) * 128 + 64 + lane] = (unsigned short)(f2u(lo) >> 16);
    }
  }
}

// ---------------- pooled head: q-circuit + MLP ----------------
__global__ __launch_bounds__(256) void k_final(
    const float* __restrict__ g, const float* __restrict__ gcnt,
    const float* __restrict__ prew, const float* __restrict__ preb,
    const float* __restrict__ qw, const float* __restrict__ pw1,
    const float* __restrict__ pb1, const float* __restrict__ pw2,
    const float* __restrict__ pb2, float* __restrict__ out) {
  const int lane = threadIdx.x & 63;
  const int gid = (blockIdx.x * 256 + threadIdx.x) >> 6;
  if (gid >= NG) return;
  const float cnt = fmaxf(gcnt[gid], 1.f);
  const float gv = g[gid * 64 + lane] / cnt;
  float qin[4];
#pragma unroll
  for (int q = 0; q < 4; ++q)
    qin[q] = wave_sum(gv * prew[lane * 4 + q]) + preb[q];
  float sr[16], si[16];
#pragma unroll
  for (int i = 0; i < 16; ++i) { sr[i] = 0.f; si[i] = 0.f; }
  sr[0] = 1.f;
#pragma unroll
  for (int q = 0; q < 4; ++q) {  // RX(qin[q])
    const int mask = 8 >> q;
    float s, c;
    __sincosf(qin[q] * 0.5f, &s, &c);
#pragma unroll
    for (int i = 0; i < 16; ++i)
      if (!(i & mask)) {
        const int j = i | mask;
        const float ar = sr[i], ai = si[i], br = sr[j], bi = si[j];
        sr[i] = c * ar + s * bi; si[i] = c * ai - s * br;
        sr[j] = c * br + s * ai; si[j] = c * bi - s * ar;
      }
  }
#pragma unroll
  for (int l = 0; l < 2; ++l) {
#pragma unroll
    for (int q = 0; q < 4; ++q) {  // RY(qw[l][q])
      const int mask = 8 >> q;
      float s, c;
      __sincosf(qw[l * 4 + q] * 0.5f, &s, &c);
#pragma unroll
      for (int i = 0; i < 16; ++i)
        if (!(i & mask)) {
          const int j = i | mask;
          const float ar = sr[i], ai = si[i], br = sr[j], bi = si[j];
          sr[i] = c * ar - s * br; si[i] = c * ai - s * bi;
          sr[j] = s * ar + c * br; si[j] = s * ai + c * bi;
        }
    }
#pragma unroll
    for (int q = 0; q < 4; ++q) {  // CNOT q -> (q+1)%4
      const int mc = 8 >> q;
      const int mt = 8 >> ((q + 1) & 3);
#pragma unroll
      for (int i = 0; i < 16; ++i)
        if ((i & mc) && !(i & mt)) {
          const int j = i | mt;
          float t = sr[i]; sr[i] = sr[j]; sr[j] = t;
          t = si[i]; si[i] = si[j]; si[j] = t;
        }
    }
  }
  float qo[4] = {0.f, 0.f, 0.f, 0.f};
#pragma unroll
  for (int i = 0; i < 16; ++i) {
    const float p = sr[i] * sr[i] + si[i] * si[i];
#pragma unroll
    for (int q = 0; q < 4; ++q) qo[q] += ((i >> (3 - q)) & 1) ? -p : p;
  }
  float t = pb1[lane];
#pragma unroll
  for (int q = 0; q < 4; ++q) t += qo[q] * pw1[q * 64 + lane];
  const float r = wave_sum(silu_f(t) * pw2[lane]);
  if (lane == 0) out[gid] = r + pb2[0];
}

extern "C" void kernel_launch(void* const* d_in, const int* in_sizes, int n_in,
                              void* d_out, int out_size, void* d_ws, size_t ws_size,
                              hipStream_t stream) {
  (void)in_sizes; (void)n_in; (void)out_size; (void)ws_size;
  const int*   nt    = (const int*)d_in[0];
  const float* pos0  = (const float*)d_in[1];
  const int*   ei    = (const int*)d_in[2];
  const float* eattr = (const float*)d_in[3];
  const int*   batch = (const int*)d_in[4];
  const float* emb   = (const float*)d_in[5];
  const float* ew1   = (const float*)d_in[6];
  const float* eb1   = (const float*)d_in[7];
  const float* ew2   = (const float*)d_in[8];
  const float* eb2   = (const float*)d_in[9];
  const float* cw1   = (const float*)d_in[10];
  const float* cb1   = (const float*)d_in[11];
  const float* cw2   = (const float*)d_in[12];
  const float* cb2   = (const float*)d_in[13];
  const float* nw1   = (const float*)d_in[14];
  const float* nb1   = (const float*)d_in[15];
  const float* nw2   = (const float*)d_in[16];
  const float* nb2   = (const float*)d_in[17];
  const float* prew  = (const float*)d_in[18];
  const float* preb  = (const float*)d_in[19];
  const float* qw    = (const float*)d_in[20];
  const float* pw1   = (const float*)d_in[21];
  const float* pb1   = (const float*)d_in[22];
  const float* pw2   = (const float*)d_in[23];
  const float* pb2   = (const float*)d_in[24];
  float* out = (float*)d_out;

  float* ws   = (float*)d_ws;
  float* h    = ws;               // NN*64
  float* pos  = h + NN * 64;      // NN*3
  float* posd = pos + NN * 3;     // NN*3
  float* agg  = posd + NN * 3;    // NN*64
  float* deg  = agg + NN * 64;    // NN
  float* g    = deg + NN;         // NG*64
  float* gcnt = g + NG * 64;      // NG
  unsigned short* hpk = (unsigned short*)(gcnt + NG);  // NN*128 bf16 (hi|lo)

  k_init_h<<<(NN * 64 + 255) / 256, 256, 0, stream>>>(nt, emb, h, hpk);
  k_prep<<<(NN * 3 + 255) / 256, 256, 0, stream>>>(pos0, pos, deg, g, gcnt);
  k_hist<<<(NE + 255) / 256, 256, 0, stream>>>(ei, deg);
  k_cnt<<<(NN + 255) / 256, 256, 0, stream>>>(batch, deg, gcnt);
  for (int l = 0; l < NL; ++l) {
    k_zero<<<(NN * 67 + 255) / 256, 256, 0, stream>>>(agg, posd);
    k_edge<<<2048, 256, 0, stream>>>(hpk, pos, ei, eattr,
        ew1 + l * 133 * 64, eb1 + l * 64, ew2 + l * 64 * 64, eb2 + l * 64,
        cw1 + l * 64 * 64, cb1 + l * 64, cw2 + l * 64, cb2 + l, agg, posd);
    k_pos<<<(NN * 3 + 255) / 256, 256, 0, stream>>>(pos, posd, deg);
    k_node<<<512, 256, 0, stream>>>(h, hpk, agg, nw1 + l * 128 * 64, nb1 + l * 64,
                                    nw2 + l * 64 * 64, nb2 + l * 64);
  }
  k_pool<<<800, 256, 0, stream>>>(h, batch, g);
  k_final<<<(NG * 64 + 255) / 256, 256, 0, stream>>>(g, gcnt, prew, preb, qw,
                                                     pw1, pb1, pw2, pb2, out);
}

// Round 4
// 1239.532 us; speedup vs baseline: 1.5913x; 1.3785x over previous
//
#include <hip/hip_runtime.h>

#define NN 50000
#define NE 800000
#define NG 128
#define NL 3
#define NPAIR (NE / 32)

typedef __attribute__((ext_vector_type(8))) short short8;
typedef __attribute__((ext_vector_type(4))) float f32x4;
typedef __attribute__((ext_vector_type(4))) int i32x4;

union FragU { i32x4 i; short8 s; };

__device__ __forceinline__ float silu_f(float x) { return x / (1.f + __expf(-x)); }
__device__ __forceinline__ float rdl(float v, int l) {
  return __int_as_float(__builtin_amdgcn_readlane(__float_as_int(v), l));
}
__device__ __forceinline__ float wave_sum(float v) {
#pragma unroll
  for (int m = 1; m < 64; m <<= 1) v += __shfl_xor(v, m, 64);
  return v;
}

__device__ __forceinline__ unsigned f2u(float x) { return __float_as_uint(x); }
__device__ __forceinline__ float hi_part(float x) {
  return __uint_as_float(f2u(x) & 0xffff0000u);
}
// pack two fp32 -> (bf16,bf16) dword via truncation; e0 in low half
__device__ __forceinline__ unsigned pk_hi(float e0, float e1) {
  return __builtin_amdgcn_perm(f2u(e1), f2u(e0), 0x07060302u);
}

__device__ __forceinline__ f32x4 mfma16(i32x4 a, i32x4 b, f32x4 c) {
  FragU ua, ub; ua.i = a; ub.i = b;
  return __builtin_amdgcn_mfma_f32_16x16x32_bf16(ua.s, ub.s, c, 0, 0, 0);
}

// split 8 fp32 into hi/lo bf16x8 fragments (element order: k ascending)
__device__ __forceinline__ void split8(const float* x, i32x4& fh, i32x4& fl) {
#pragma unroll
  for (int i = 0; i < 4; ++i) {
    const float a = x[2 * i], b = x[2 * i + 1];
    fh[i] = (int)pk_hi(a, b);
    fl[i] = (int)pk_hi(a - hi_part(a), b - hi_part(b));
  }
}

// bounded B-frag (hi/lo) for W[k][n]: rows k0..k0+31, col n (ld=64)
__device__ __forceinline__ void wfrag(const float* __restrict__ W, int nrows, int k0,
                                      int n, int lane, i32x4& fh, i32x4& fl) {
  const int kb = k0 + ((lane >> 4) << 3);
  float x[8];
#pragma unroll
  for (int j = 0; j < 8; ++j) {
    const int k = kb + j;
    x[j] = (k < nrows) ? W[k * 64 + n] : 0.f;
  }
  split8(x, fh, fl);
}

// ---------------- init / small kernels ----------------
__global__ __launch_bounds__(256) void k_init_h(const int* __restrict__ nt,
                                                const float* __restrict__ emb,
                                                float* __restrict__ h,
                                                unsigned short* __restrict__ hpk) {
  int idx = blockIdx.x * 256 + threadIdx.x;
  if (idx < NN * 64) {
    const int node = idx >> 6, c = idx & 63;
    const float v = emb[nt[node] * 64 + c];
    h[idx] = v;
    const unsigned hb = f2u(v) & 0xffff0000u;
    const float lo = v - __uint_as_float(hb);
    hpk[node * 128 + c] = (unsigned short)(hb >> 16);
    hpk[node * 128 + 64 + c] = (unsigned short)(f2u(lo) >> 16);
  }
}

__global__ __launch_bounds__(256) void k_prep(const float* __restrict__ pos_in,
                                              float* __restrict__ pos,
                                              float* __restrict__ deg,
                                              float* __restrict__ g,
                                              float* __restrict__ gcnt) {
  int idx = blockIdx.x * 256 + threadIdx.x;
  if (idx < NN * 3) pos[idx] = pos_in[idx];
  if (idx < NN) deg[idx] = 0.f;
  if (idx < NG * 64) g[idx] = 0.f;
  if (idx < NG) gcnt[idx] = 0.f;
}

__global__ __launch_bounds__(256) void k_hist(const int* __restrict__ ei,
                                              float* __restrict__ deg) {
  int e = blockIdx.x * 256 + threadIdx.x;
  if (e < NE) atomicAdd(&deg[ei[NE + e]], 1.f);
}

__global__ __launch_bounds__(256) void k_cnt(const int* __restrict__ batch,
                                             float* __restrict__ deg,
                                             float* __restrict__ gcnt) {
  int i = blockIdx.x * 256 + threadIdx.x;
  if (i < NN) {
    deg[i] = fmaxf(deg[i], 1.f);
    atomicAdd(&gcnt[batch[i]], 1.f);
  }
}

__global__ __launch_bounds__(256) void k_zero(float* __restrict__ agg,
                                              float* __restrict__ posd) {
  int idx = blockIdx.x * 256 + threadIdx.x;
  if (idx < NN * 64) agg[idx] = 0.f;
  else if (idx < NN * 64 + NN * 3) posd[idx - NN * 64] = 0.f;
}

__global__ __launch_bounds__(256) void k_pos(float* __restrict__ pos,
                                             const float* __restrict__ posd,
                                             const float* __restrict__ deg) {
  int idx = blockIdx.x * 256 + threadIdx.x;
  if (idx < NN * 3) pos[idx] += posd[idx] / deg[idx / 3];
}

// run-length pooled over sorted batch
__global__ __launch_bounds__(256) void k_pool(const float* __restrict__ h,
                                              const int* __restrict__ batch,
                                              float* __restrict__ g) {
  const int lane = threadIdx.x & 63;
  const int wid = (blockIdx.x * 256 + threadIdx.x) >> 6;
  const int nw = (gridDim.x * 256) >> 6;
  for (int n0 = wid * 16; n0 < NN; n0 += nw * 16) {
    float acc = 0.f;
    int curb = batch[n0];
#pragma unroll
    for (int i = 0; i < 16; ++i) {
      const int b = batch[n0 + i];
      const float v = h[(size_t)(n0 + i) * 64 + lane];
      if (b != curb) {
        atomicAdd(&g[curb * 64 + lane], acc);
        acc = 0.f;
        curb = b;
      }
      acc += v;
    }
    atomicAdd(&g[curb * 64 + lane], acc);
  }
}

// ---------------- edge message kernel (wave-solo, barrier-free) ----------------
// 8-wave block (512 thr). Each WAVE owns 32 edges/iter (tiles A,B) end-to-end,
// all 64 output cols. Shared state: read-only weight-frag table in LDS (72KB,
// staged once, single barrier). Per-wave private 8KB m1/mm planes (XOR-swizzled,
// DS in-order within a wave -> NO barriers in the main loop). Atomics issued and
// never waited on -> no vmcnt(0) drains. 1 block/CU (136KB LDS), 2 waves/SIMD.
//
// Weight table (i32x4 idx): w1h[(s*4+t)*64+lane] s=0..4 (s=4 = tail rows
// 128..132, zero-padded); w1l +1280; w2h 2560+; w2l 3072+; c1h 3584+; c1l 4096+.
// m1/mm plane: [16 rows][128B] hi (+2048B lo), byte = row*128 +
// ((col*2) ^ ((row&7)<<4)).  Write: even-m lanes pack col pairs (shfl_xor 1).
__global__ __launch_bounds__(512, 2) void k_edge(
    const unsigned short* __restrict__ hpk, const float* __restrict__ pos,
    const int* __restrict__ ei, const float* __restrict__ eattr,
    const float* __restrict__ W1, const float* __restrict__ B1,
    const float* __restrict__ W2, const float* __restrict__ B2,
    const float* __restrict__ C1, const float* __restrict__ CB1,
    const float* __restrict__ C2, const float* __restrict__ CB2,
    float* __restrict__ agg, float* __restrict__ posd) {
  __shared__ i32x4 smem[8704];  // 72KB table + 8 waves * 8KB buffers = 136KB

  const int tid = threadIdx.x;
  const int lane = tid & 63;
  const int w = tid >> 6;
  const int m = lane & 15;
  const int quad = lane >> 4;

  // ---- one-time: stage weight fragment tables (36 jobs over 8 waves) ----
  for (int j = w; j < 36; j += 8) {
    int s, t, nrows, hb, lb;
    const float* W;
    if (j < 20)      { s = j >> 2; t = j & 3; W = W1; nrows = 133; hb = 0; lb = 1280; }
    else if (j < 28) { const int q = j - 20; s = q >> 2; t = q & 3; W = W2; nrows = 64; hb = 2560; lb = 3072; }
    else             { const int q = j - 28; s = q >> 2; t = q & 3; W = C1; nrows = 64; hb = 3584; lb = 4096; }
    i32x4 fh, fl;
    wfrag(W, nrows, 32 * s, t * 16 + m, lane, fh, fl);
    smem[hb + (s * 4 + t) * 64 + lane] = fh;
    smem[lb + (s * 4 + t) * 64 + lane] = fl;
  }
  __syncthreads();

  // per-lane scalars
  float eb1t[4], eb2t[4], cb1t[4], cw2t[4];
#pragma unroll
  for (int t = 0; t < 4; ++t) {
    eb1t[t] = B1[t * 16 + m];
    eb2t[t] = B2[t * 16 + m];
    cb1t[t] = CB1[t * 16 + m];
    cw2t[t] = C2[t * 16 + m];
  }
  const float cb2v = CB2[0];

  char* wb = (char*)(smem + 4608) + w * 8192;  // wave-private buffers
  char* m1A = wb;            // hi @0, lo @+2048
  char* m1B = wb + 4096;     // hi @0, lo @+2048
  const char* hB = (const char*)hpk;

  const int gw0 = blockIdx.x * 8 + w;
  const int nwv = gridDim.x * 8;

  int esA = 0, edA = 0, esB = 0, edB = 0;
  if (gw0 < NPAIR) {
    const int b = gw0 * 32 + m;
    esA = ei[b]; edA = ei[NE + b]; esB = ei[b + 16]; edB = ei[NE + b + 16];
  }

#define STORE_PAIR(base, row, toff, v)                                        \
  {                                                                           \
    const float vp_ = __shfl_xor((v), 1, 64);                                 \
    if (!(m & 1)) {                                                           \
      const int off_ = (row) * 128 + ((((toff) + m * 2)) ^ (((row) & 7) << 4)); \
      *(unsigned*)((base) + off_) = pk_hi((v), vp_);                          \
      *(unsigned*)((base) + 2048 + off_) =                                    \
          pk_hi((v)-hi_part(v), vp_ - hi_part(vp_));                          \
    }                                                                         \
  }

  for (int g = gw0; g < NPAIR; g += nwv) {
    const int e0 = g * 32;
    const int cesA = esA, cedA = edA, cesB = esB, cedB = edB;
    const int g2 = g + nwv;
    if (g2 < NPAIR) {
      const int b = g2 * 32 + m;
      esA = ei[b]; edA = ei[NE + b]; esB = ei[b + 16]; edB = ei[NE + b + 16];
    }

    // ---- gathers: lane's own edge (m) node rows, frag-ready ----
    i32x4 fha[4], fla[4], fhb[4], flb[4];
#pragma unroll
    for (int s = 0; s < 4; ++s) {
      const unsigned node = (unsigned)(s < 2 ? cedA : cesA);
      const unsigned off = node * 256u + (unsigned)((s & 1) * 64 + quad * 16);
      fha[s] = *(const i32x4*)(hB + off);
      fla[s] = *(const i32x4*)(hB + off + 128);
    }
#pragma unroll
    for (int s = 0; s < 4; ++s) {
      const unsigned node = (unsigned)(s < 2 ? cedB : cesB);
      const unsigned off = node * 256u + (unsigned)((s & 1) * 64 + quad * 16);
      fhb[s] = *(const i32x4*)(hB + off);
      flb[s] = *(const i32x4*)(hB + off + 128);
    }

    // ---- per-edge tail data: lanes 0..15 tile A, 16..31 tile B ----
    float rx = 0.f, ry = 0.f, rz = 0.f, d2v = 0.f;
    float ea0 = 0.f, ea1 = 0.f, ea2 = 0.f, ea3 = 0.f;
    if (lane < 32) {
      const int s_ = (lane < 16) ? cesA : cesB;
      const int d_ = (lane < 16) ? cedA : cedB;
      rx = pos[d_ * 3 + 0] - pos[s_ * 3 + 0];
      ry = pos[d_ * 3 + 1] - pos[s_ * 3 + 1];
      rz = pos[d_ * 3 + 2] - pos[s_ * 3 + 2];
      d2v = rx * rx + ry * ry + rz * rz;
      const float4 ea = *(const float4*)(eattr + 4 * (e0 + lane));
      ea0 = ea.x; ea1 = ea.y; ea2 = ea.z; ea3 = ea.w;
    }

    // tail A-frags (k = 128..159): quad 0 = [d2, ea0..3, 0,0,0], quads 1-3 zero
    i32x4 thA, tlA, thB, tlB;
    {
      float x0 = __shfl(d2v, m), x1 = __shfl(ea0, m), x2 = __shfl(ea1, m),
            x3 = __shfl(ea2, m), x4 = __shfl(ea3, m);
      if (quad) { x0 = x1 = x2 = x3 = x4 = 0.f; }
      float xa[8] = {x0, x1, x2, x3, x4, 0.f, 0.f, 0.f};
      split8(xa, thA, tlA);
    }
    {
      float x0 = __shfl(d2v, 16 + m), x1 = __shfl(ea0, 16 + m), x2 = __shfl(ea1, 16 + m),
            x3 = __shfl(ea2, 16 + m), x4 = __shfl(ea3, 16 + m);
      if (quad) { x0 = x1 = x2 = x3 = x4 = 0.f; }
      float xb[8] = {x0, x1, x2, x3, x4, 0.f, 0.f, 0.f};
      split8(xb, thB, tlB);
    }

    // ---- GEMV1: m_in[16x160] @ W1[160x64], both tiles, all 4 n-tiles ----
#pragma unroll
    for (int t = 0; t < 4; ++t) {
      f32x4 PA = {eb1t[t], eb1t[t], eb1t[t], eb1t[t]}, QA = {0.f, 0.f, 0.f, 0.f};
      f32x4 PB = {eb1t[t], eb1t[t], eb1t[t], eb1t[t]}, QB = {0.f, 0.f, 0.f, 0.f};
#pragma unroll
      for (int s = 0; s < 4; ++s) {
        const i32x4 wh = smem[(s * 4 + t) * 64 + lane];
        const i32x4 wl = smem[1280 + (s * 4 + t) * 64 + lane];
        PA = mfma16(fha[s], wh, PA);
        QA = mfma16(fha[s], wl, QA);
        QA = mfma16(fla[s], wh, QA);
        PB = mfma16(fhb[s], wh, PB);
        QB = mfma16(fhb[s], wl, QB);
        QB = mfma16(flb[s], wh, QB);
      }
      {  // tail k-step (s=4)
        const i32x4 wh = smem[(16 + t) * 64 + lane];
        const i32x4 wl = smem[1280 + (16 + t) * 64 + lane];
        PA = mfma16(thA, wh, PA);
        QA = mfma16(thA, wl, QA);
        QA = mfma16(tlA, wh, QA);
        PB = mfma16(thB, wh, PB);
        QB = mfma16(thB, wl, QB);
        QB = mfma16(tlB, wh, QB);
      }
#pragma unroll
      for (int r = 0; r < 4; ++r) {
        const int row = quad * 4 + r;
        const float vA = silu_f(PA[r] + QA[r]);
        const float vB = silu_f(PB[r] + QB[r]);
        STORE_PAIR(m1A, row, t * 32, vA);
        STORE_PAIR(m1B, row, t * 32, vB);
      }
    }

    // agg destination nodes (per output row)
    int rdA[4], rdB[4];
#pragma unroll
    for (int r = 0; r < 4; ++r) {
      rdA[r] = __shfl(cedA, quad * 4 + r, 64);
      rdB[r] = __shfl(cedB, quad * 4 + r, 64);
    }

    // ---- GEMV2: m1[16x64] @ W2[64x64] ----
    i32x4 a1hA[2], a1lA[2], a1hB[2], a1lB[2];
#pragma unroll
    for (int s = 0; s < 2; ++s) {
      const int off = m * 128 + ((s * 64 + quad * 16) ^ ((m & 7) << 4));
      a1hA[s] = *(const i32x4*)(m1A + off);
      a1lA[s] = *(const i32x4*)(m1A + 2048 + off);
      a1hB[s] = *(const i32x4*)(m1B + off);
      a1lB[s] = *(const i32x4*)(m1B + 2048 + off);
    }
#pragma unroll
    for (int t = 0; t < 4; ++t) {
      f32x4 PA = {eb2t[t], eb2t[t], eb2t[t], eb2t[t]}, QA = {0.f, 0.f, 0.f, 0.f};
      f32x4 PB = {eb2t[t], eb2t[t], eb2t[t], eb2t[t]}, QB = {0.f, 0.f, 0.f, 0.f};
#pragma unroll
      for (int s = 0; s < 2; ++s) {
        const i32x4 wh = smem[2560 + (s * 4 + t) * 64 + lane];
        const i32x4 wl = smem[3072 + (s * 4 + t) * 64 + lane];
        PA = mfma16(a1hA[s], wh, PA);
        QA = mfma16(a1hA[s], wl, QA);
        QA = mfma16(a1lA[s], wh, QA);
        PB = mfma16(a1hB[s], wh, PB);
        QB = mfma16(a1hB[s], wl, QB);
        QB = mfma16(a1lB[s], wh, QB);
      }
#pragma unroll
      for (int r = 0; r < 4; ++r) {
        const int row = quad * 4 + r;
        const float mA = silu_f(PA[r] + QA[r]);
        const float mB = silu_f(PB[r] + QB[r]);
        STORE_PAIR(m1A, row, t * 32, mA);  // mm overwrites m1 (in-order DS)
        STORE_PAIR(m1B, row, t * 32, mB);
        atomicAdd(&agg[(size_t)rdA[r] * 64 + t * 16 + m], mA);
        atomicAdd(&agg[(size_t)rdB[r] * 64 + t * 16 + m], mB);
      }
    }

    // ---- coord MLP: silu(mm @ C1 + cb1) . cw2, summed over 64 cols ----
    i32x4 mhA[2], mlA[2], mhB[2], mlB[2];
#pragma unroll
    for (int s = 0; s < 2; ++s) {
      const int off = m * 128 + ((s * 64 + quad * 16) ^ ((m & 7) << 4));
      mhA[s] = *(const i32x4*)(m1A + off);
      mlA[s] = *(const i32x4*)(m1A + 2048 + off);
      mhB[s] = *(const i32x4*)(m1B + off);
      mlB[s] = *(const i32x4*)(m1B + 2048 + off);
    }
    float trA[4] = {0.f, 0.f, 0.f, 0.f}, trB[4] = {0.f, 0.f, 0.f, 0.f};
#pragma unroll
    for (int t = 0; t < 4; ++t) {
      f32x4 PA = {cb1t[t], cb1t[t], cb1t[t], cb1t[t]}, QA = {0.f, 0.f, 0.f, 0.f};
      f32x4 PB = {cb1t[t], cb1t[t], cb1t[t], cb1t[t]}, QB = {0.f, 0.f, 0.f, 0.f};
#pragma unroll
      for (int s = 0; s < 2; ++s) {
        const i32x4 wh = smem[3584 + (s * 4 + t) * 64 + lane];
        const i32x4 wl = smem[4096 + (s * 4 + t) * 64 + lane];
        PA = mfma16(mhA[s], wh, PA);
        QA = mfma16(mhA[s], wl, QA);
        QA = mfma16(mlA[s], wh, QA);
        PB = mfma16(mhB[s], wh, PB);
        QB = mfma16(mhB[s], wl, QB);
        QB = mfma16(mlB[s], wh, QB);
      }
#pragma unroll
      for (int r = 0; r < 4; ++r) {
        trA[r] += silu_f(PA[r] + QA[r]) * cw2t[t];
        trB[r] += silu_f(PB[r] + QB[r]) * cw2t[t];
      }
    }
#pragma unroll
    for (int mask = 1; mask < 16; mask <<= 1)
#pragma unroll
      for (int r = 0; r < 4; ++r) {
        trA[r] += __shfl_xor(trA[r], mask, 64);
        trB[r] += __shfl_xor(trB[r], mask, 64);
      }
    // posd atomics: lane (rr = m>>2 -> row, cc = m&3 -> coord), per quad
    {
      const int rr = m >> 2, cc = m & 3;
      const int e = quad * 4 + rr;
      const float tA = ((rr & 2) ? ((rr & 1) ? trA[3] : trA[2])
                                 : ((rr & 1) ? trA[1] : trA[0])) + cb2v;
      const float tB = ((rr & 2) ? ((rr & 1) ? trB[3] : trB[2])
                                 : ((rr & 1) ? trB[1] : trB[0])) + cb2v;
      const int dA_ = __shfl(cedA, e, 64);
      const int dB_ = __shfl(cedB, e, 64);
      const float axA = __shfl(rx, e, 64), ayA = __shfl(ry, e, 64), azA = __shfl(rz, e, 64);
      const float axB = __shfl(rx, 16 + e, 64), ayB = __shfl(ry, 16 + e, 64), azB = __shfl(rz, 16 + e, 64);
      if (cc < 3) {
        const float relA = cc == 0 ? axA : (cc == 1 ? ayA : azA);
        const float relB = cc == 0 ? axB : (cc == 1 ? ayB : azB);
        atomicAdd(&posd[dA_ * 3 + cc], relA * tA);
        atomicAdd(&posd[dB_ * 3 + cc], relB * tB);
      }
    }
  }
#undef STORE_PAIR
}

// ---------------- node update kernel (8-node batch per wave) ----------------
__global__ __launch_bounds__(256) void k_node(
    float* __restrict__ h, unsigned short* __restrict__ hpk,
    const float* __restrict__ agg,
    const float* __restrict__ W1, const float* __restrict__ B1,
    const float* __restrict__ W2, const float* __restrict__ B2) {
  __shared__ float sW1[128 * 64];
  __shared__ float sW2[64 * 64];
  for (int i = threadIdx.x; i < 128 * 64; i += 256) sW1[i] = W1[i];
  for (int i = threadIdx.x; i < 64 * 64; i += 256) sW2[i] = W2[i];
  __syncthreads();
  const int lane = threadIdx.x & 63;
  const float nb1 = B1[lane], nb2 = B2[lane];
  const int wid = (blockIdx.x * 256 + threadIdx.x) >> 6;
  const int nw = (gridDim.x * 256) >> 6;
  for (int n0 = wid * 8; n0 < NN; n0 += nw * 8) {
    float hj[8], aj[8], a1[8];
#pragma unroll
    for (int i = 0; i < 8; ++i) {
      hj[i] = h[(size_t)(n0 + i) * 64 + lane];
      aj[i] = agg[(size_t)(n0 + i) * 64 + lane];
      a1[i] = nb1;
    }
#pragma unroll
    for (int k = 0; k < 64; ++k) {
      const float wv = sW1[k * 64 + lane];
#pragma unroll
      for (int i = 0; i < 8; ++i) a1[i] += rdl(hj[i], k) * wv;
    }
#pragma unroll
    for (int k = 0; k < 64; ++k) {
      const float wv = sW1[(64 + k) * 64 + lane];
#pragma unroll
      for (int i = 0; i < 8; ++i) a1[i] += rdl(aj[i], k) * wv;
    }
    float u[8], a2[8];
#pragma unroll
    for (int i = 0; i < 8; ++i) { u[i] = silu_f(a1[i]); a2[i] = nb2; }
#pragma unroll
    for (int k = 0; k < 64; ++k) {
      const float wv = sW2[k * 64 + lane];
#pragma unroll
      for (int i = 0; i < 8; ++i) a2[i] += rdl(u[i], k) * wv;
    }
#pragma unroll
    for (int i = 0; i < 8; ++i) {
      const float hn = hj[i] + a2[i];
      h[(size_t)(n0 + i) * 64 + lane] = hn;
      const unsigned hb = f2u(hn) & 0xffff0000u;
      const float lo = hn - __uint_as_float(hb);
      hpk[(size_t)(n0 + i) * 128 + lane] = (unsigned short)(hb >> 16);
      hpk[(size_t)(n0 + i) * 128 + 64 + lane] = (unsigned short)(f2u(lo) >> 16);
    }
  }
}

// ---------------- pooled head: q-circuit + MLP ----------------
__global__ __launch_bounds__(256) void k_final(
    const float* __restrict__ g, const float* __restrict__ gcnt,
    const float* __restrict__ prew, const float* __restrict__ preb,
    const float* __restrict__ qw, const float* __restrict__ pw1,
    const float* __restrict__ pb1, const float* __restrict__ pw2,
    const float* __restrict__ pb2, float* __restrict__ out) {
  const int lane = threadIdx.x & 63;
  const int gid = (blockIdx.x * 256 + threadIdx.x) >> 6;
  if (gid >= NG) return;
  const float cnt = fmaxf(gcnt[gid], 1.f);
  const float gv = g[gid * 64 + lane] / cnt;
  float qin[4];
#pragma unroll
  for (int q = 0; q < 4; ++q)
    qin[q] = wave_sum(gv * prew[lane * 4 + q]) + preb[q];
  float sr[16], si[16];
#pragma unroll
  for (int i = 0; i < 16; ++i) { sr[i] = 0.f; si[i] = 0.f; }
  sr[0] = 1.f;
#pragma unroll
  for (int q = 0; q < 4; ++q) {  // RX(qin[q])
    const int mask = 8 >> q;
    float s, c;
    __sincosf(qin[q] * 0.5f, &s, &c);
#pragma unroll
    for (int i = 0; i < 16; ++i)
      if (!(i & mask)) {
        const int j = i | mask;
        const float ar = sr[i], ai = si[i], br = sr[j], bi = si[j];
        sr[i] = c * ar + s * bi; si[i] = c * ai - s * br;
        sr[j] = c * br + s * ai; si[j] = c * bi - s * ar;
      }
  }
#pragma unroll
  for (int l = 0; l < 2; ++l) {
#pragma unroll
    for (int q = 0; q < 4; ++q) {  // RY(qw[l][q])
      const int mask = 8 >> q;
      float s, c;
      __sincosf(qw[l * 4 + q] * 0.5f, &s, &c);
#pragma unroll
      for (int i = 0; i < 16; ++i)
        if (!(i & mask)) {
          const int j = i | mask;
          const float ar = sr[i], ai = si[i], br = sr[j], bi = si[j];
          sr[i] = c * ar - s * br; si[i] = c * ai - s * bi;
          sr[j] = s * ar + c * br; si[j] = s * ai + c * bi;
        }
    }
#pragma unroll
    for (int q = 0; q < 4; ++q) {  // CNOT q -> (q+1)%4
      const int mc = 8 >> q;
      const int mt = 8 >> ((q + 1) & 3);
#pragma unroll
      for (int i = 0; i < 16; ++i)
        if ((i & mc) && !(i & mt)) {
          const int j = i | mt;
          float t = sr[i]; sr[i] = sr[j]; sr[j] = t;
          t = si[i]; si[i] = si[j]; si[j] = t;
        }
    }
  }
  float qo[4] = {0.f, 0.f, 0.f, 0.f};
#pragma unroll
  for (int i = 0; i < 16; ++i) {
    const float p = sr[i] * sr[i] + si[i] * si[i];
#pragma unroll
    for (int q = 0; q < 4; ++q) qo[q] += ((i >> (3 - q)) & 1) ? -p : p;
  }
  float t = pb1[lane];
#pragma unroll
  for (int q = 0; q < 4; ++q) t += qo[q] * pw1[q * 64 + lane];
  const float r = wave_sum(silu_f(t) * pw2[lane]);
  if (lane == 0) out[gid] = r + pb2[0];
}

extern "C" void kernel_launch(void* const* d_in, const int* in_sizes, int n_in,
                              void* d_out, int out_size, void* d_ws, size_t ws_size,
                              hipStream_t stream) {
  (void)in_sizes; (void)n_in; (void)out_size; (void)ws_size;
  const int*   nt    = (const int*)d_in[0];
  const float* pos0  = (const float*)d_in[1];
  const int*   ei    = (const int*)d_in[2];
  const float* eattr = (const float*)d_in[3];
  const int*   batch = (const int*)d_in[4];
  const float* emb   = (const float*)d_in[5];
  const float* ew1   = (const float*)d_in[6];
  const float* eb1   = (const float*)d_in[7];
  const float* ew2   = (const float*)d_in[8];
  const float* eb2   = (const float*)d_in[9];
  const float* cw1   = (const float*)d_in[10];
  const float* cb1   = (const float*)d_in[11];
  const float* cw2   = (const float*)d_in[12];
  const float* cb2   = (const float*)d_in[13];
  const float* nw1   = (const float*)d_in[14];
  const float* nb1   = (const float*)d_in[15];
  const float* nw2   = (const float*)d_in[16];
  const float* nb2   = (const float*)d_in[17];
  const float* prew  = (const float*)d_in[18];
  const float* preb  = (const float*)d_in[19];
  const float* qw    = (const float*)d_in[20];
  const float* pw1   = (const float*)d_in[21];
  const float* pb1   = (const float*)d_in[22];
  const float* pw2   = (const float*)d_in[23];
  const float* pb2   = (const float*)d_in[24];
  float* out = (float*)d_out;

  float* ws   = (float*)d_ws;
  float* h    = ws;               // NN*64
  float* pos  = h + NN * 64;      // NN*3
  float* posd = pos + NN * 3;     // NN*3
  float* agg  = posd + NN * 3;    // NN*64
  float* deg  = agg + NN * 64;    // NN
  float* g    = deg + NN;         // NG*64
  float* gcnt = g + NG * 64;      // NG
  unsigned short* hpk = (unsigned short*)(gcnt + NG);  // NN*128 bf16 (hi|lo)

  k_init_h<<<(NN * 64 + 255) / 256, 256, 0, stream>>>(nt, emb, h, hpk);
  k_prep<<<(NN * 3 + 255) / 256, 256, 0, stream>>>(pos0, pos, deg, g, gcnt);
  k_hist<<<(NE + 255) / 256, 256, 0, stream>>>(ei, deg);
  k_cnt<<<(NN + 255) / 256, 256, 0, stream>>>(batch, deg, gcnt);
  for (int l = 0; l < NL; ++l) {
    k_zero<<<(NN * 67 + 255) / 256, 256, 0, stream>>>(agg, posd);
    k_edge<<<256, 512, 0, stream>>>(hpk, pos, ei, eattr,
        ew1 + l * 133 * 64, eb1 + l * 64, ew2 + l * 64 * 64, eb2 + l * 64,
        cw1 + l * 64 * 64, cb1 + l * 64, cw2 + l * 64, cb2 + l, agg, posd);
    k_pos<<<(NN * 3 + 255) / 256, 256, 0, stream>>>(pos, posd, deg);
    k_node<<<512, 256, 0, stream>>>(h, hpk, agg, nw1 + l * 128 * 64, nb1 + l * 64,
                                    nw2 + l * 64 * 64, nb2 + l * 64);
  }
  k_pool<<<800, 256, 0, stream>>>(h, batch, g);
  k_final<<<(NG * 64 + 255) / 256, 256, 0, stream>>>(g, gcnt, prew, preb, qw,
                                                     pw1, pb1, pw2, pb2, out);
}